// Round 1
// 1426.107 us; speedup vs baseline: 1.1874x; 1.1874x over previous
//
#include <hip/hip_runtime.h>
#include <stdint.h>

#define B_ 16
#define V_ 40000
#define C_ 128
#define H_ 56
#define W_ 56
#define E_ 120000
#define M_ (V_*B_)   // 640000 rows

typedef float f32x4 __attribute__((ext_vector_type(4)));
typedef __bf16 bf16x8 __attribute__((ext_vector_type(8)));

// Big scratch in device globals (fully rewritten every call; no cross-call state).
__device__ __align__(16) uint16_t g_bufA[(size_t)M_*C_];   // g, then t  (bf16, [V,B,C])
__device__ __align__(16) uint16_t g_bufD[(size_t)M_*C_];   // d (conv1 out, residual)
__device__ __align__(16) uint16_t g_bhwc[(size_t)B_*H_*W_*C_]; // img feats -> [B,H,W,C] bf16
__device__ __align__(16) uint16_t g_wf[6][C_*C_];          // frag-ordered weights (A-operand)
__device__ int g_cnt[V_];
__device__ int g_rowptr[V_+1];
__device__ int g_cursor[V_];
__device__ int g_adj[2*E_];
__device__ int g_blksum[64];

__device__ inline float bf_lo(uint32_t u){ return __builtin_bit_cast(float, u<<16); }
__device__ inline float bf_hi(uint32_t u){ return __builtin_bit_cast(float, u & 0xffff0000u); }
__device__ inline uint32_t f2bf(float f){ uint32_t u = __builtin_bit_cast(uint32_t,f); return (u + 0x7fffu + ((u>>16)&1u))>>16; }
__device__ inline uint32_t pk2(float lo, float hi){ return f2bf(lo) | (f2bf(hi)<<16); }

__device__ inline uint16_t* big_buf(int s){ return s==0 ? g_bufA : g_bufD; }

// ---------------- CSR build ----------------
__global__ void k_zero(){
  int i = blockIdx.x*256 + threadIdx.x;
  if (i < V_) g_cnt[i] = 0;
}
__global__ void k_count(const int* __restrict__ ed){
  int e = blockIdx.x*256 + threadIdx.x;
  if (e < E_){
    atomicAdd(&g_cnt[ed[2*e]],1);
    atomicAdd(&g_cnt[ed[2*e+1]],1);
  }
}
// hierarchical exclusive scan over g_cnt -> g_rowptr (3 small kernels)
__global__ __launch_bounds__(1024) void k_scan1(){
  __shared__ int sd[1024];
  int idx = blockIdx.x*1024 + (int)threadIdx.x;
  int vl = (idx<V_)? g_cnt[idx] : 0;
  sd[threadIdx.x] = vl;
  __syncthreads();
  #pragma unroll
  for (int off=1; off<1024; off<<=1){
    int t = ((int)threadIdx.x >= off) ? sd[threadIdx.x-off] : 0;
    __syncthreads();
    sd[threadIdx.x] += t;
    __syncthreads();
  }
  if (idx<V_) g_rowptr[idx] = sd[threadIdx.x] - vl;   // block-local exclusive
  if (threadIdx.x==1023) g_blksum[blockIdx.x] = sd[1023];
}
__global__ void k_scan2(){
  if (threadIdx.x==0){
    int s = 0;
    for (int i=0;i<40;++i){ int t = g_blksum[i]; g_blksum[i] = s; s += t; }
    g_rowptr[V_] = s;   // == 2*E_
  }
}
__global__ __launch_bounds__(1024) void k_scan3(){
  int idx = blockIdx.x*1024 + (int)threadIdx.x;
  if (idx<V_){
    int r = g_rowptr[idx] + g_blksum[blockIdx.x];
    g_rowptr[idx] = r;
    g_cursor[idx] = r;
  }
}
__global__ void k_fill(const int* __restrict__ ed){
  int e = blockIdx.x*256 + threadIdx.x;
  if (e < E_){
    int i = ed[2*e], j = ed[2*e+1];
    int p = atomicAdd(&g_cursor[i],1); g_adj[p] = j;
    int q = atomicAdd(&g_cursor[j],1); g_adj[q] = i;
  }
}

// ---------------- img_features [B,C,H,W] f32 -> [B,H,W,C] bf16 ----------------
__global__ __launch_bounds__(256) void k_transpose(const float* __restrict__ feat){
  int idx = blockIdx.x*256 + threadIdx.x;
  int c = idx & (C_-1);
  int p = idx >> 7;            // (b*H + y)*W + x
  int x = p % W_;
  int q = p / W_;
  int y = q % H_;
  int b = q / H_;
  g_bhwc[idx] = (uint16_t)f2bf(feat[(((size_t)b*C_ + c)*H_ + y)*W_ + x]);
}

// ---------------- weights f32 -> MFMA A-operand fragment order (bf16) ----------------
// frag element (nt,ks,lane,j) = W[k = ks*32 + (lane>>4)*8 + j][n = nt*16 + (lane&15)]
__global__ void k_wprep(const float* w0,const float* w1,const float* w2,
                        const float* w3,const float* w4,const float* w5){
  int tid = blockIdx.x*256 + threadIdx.x;   // 12288 threads total
  int lane = tid & 63;
  int ks = (tid>>6)&3;
  int nt = (tid>>8)&7;
  int mat = tid>>11;
  const float* wsrc = w0;
  switch(mat){ case 1: wsrc=w1; break; case 2: wsrc=w2; break;
               case 3: wsrc=w3; break; case 4: wsrc=w4; break;
               case 5: wsrc=w5; break; default: break; }
  int n  = nt*16 + (lane&15);
  int kb = ks*32 + ((lane>>4)&3)*8;
  uint4 o;
  o.x = pk2(wsrc[(kb+0)*C_+n], wsrc[(kb+1)*C_+n]);
  o.y = pk2(wsrc[(kb+2)*C_+n], wsrc[(kb+3)*C_+n]);
  o.z = pk2(wsrc[(kb+4)*C_+n], wsrc[(kb+5)*C_+n]);
  o.w = pk2(wsrc[(kb+6)*C_+n], wsrc[(kb+7)*C_+n]);
  *(uint4*)&g_wf[mat][((nt*4+ks)*64+lane)*8] = o;
}

// ---------------- vert_align + vertex_padded -> g (bufA, [V,B,C] bf16) ----------------
// One 256-thread block per vertex: thread = (b, 8-channel chunk). uint4 everywhere.
__global__ __launch_bounds__(256) void k_vertalign(const float* __restrict__ vpos,
                                                   const float* __restrict__ vpad){
  int v = blockIdx.x;
  int t = threadIdx.x;
  int b = t >> 4;
  int c0 = (t & 15) * 8;
  float px = vpos[((size_t)b*V_+v)*3 + 0];
  float py = vpos[((size_t)b*V_+v)*3 + 1];
  float fx = (px+1.f)*0.5f*(float)(W_-1);
  float fy = (py+1.f)*0.5f*(float)(H_-1);
  float x0f = floorf(fx), y0f = floorf(fy);
  float wx1 = fx-x0f, wy1 = fy-y0f;
  float wx0 = 1.f-wx1, wy0 = 1.f-wy1;
  int x0 = (int)x0f, y0 = (int)y0f;

  float4 p0 = *(const float4*)(vpad + ((size_t)b*V_+v)*C_ + c0);
  float4 p1 = *(const float4*)(vpad + ((size_t)b*V_+v)*C_ + c0 + 4);
  float a0=p0.x, a1=p0.y, a2=p0.z, a3=p0.w, a4=p1.x, a5=p1.y, a6=p1.z, a7=p1.w;
  #pragma unroll
  for (int tap=0;tap<4;++tap){
    int xi = x0 + (tap&1), yi = y0 + (tap>>1);
    float wt = ((tap&1)? wx1 : wx0) * ((tap>>1)? wy1 : wy0);
    if (xi<0||xi>=W_||yi<0||yi>=H_) wt = 0.f;   // zero-pad via weight (matches ref)
    int xc = min(max(xi,0),W_-1), yc = min(max(yi,0),H_-1);
    uint4 u = *(const uint4*)(g_bhwc + ((size_t)(b*H_+yc)*W_ + xc)*C_ + c0);
    a0 += bf_lo(u.x)*wt; a1 += bf_hi(u.x)*wt;
    a2 += bf_lo(u.y)*wt; a3 += bf_hi(u.y)*wt;
    a4 += bf_lo(u.z)*wt; a5 += bf_hi(u.z)*wt;
    a6 += bf_lo(u.w)*wt; a7 += bf_hi(u.w)*wt;
  }
  uint4 o = { pk2(a0,a1), pk2(a2,a3), pk2(a4,a5), pk2(a6,a7) };
  *(uint4*)(g_bufA + ((size_t)v*B_+b)*C_ + c0) = o;
}

// ---------------- fused conv: out = x@W0 + (A x)@W1 + b0 (+d for final) ----------------
// Neighbor aggregation (CSR gather, f32 accumulate, bf16 repack) fused into the GEMM.
// Two-phase weight staging (32 KB LDS): W0 pass with xf, then W1 pass with zf.
union FragCvt { uint4 u; bf16x8 v; };

__global__ __launch_bounds__(256,3) void k_conv(int conv, int xsel,
                                                const float* __restrict__ bias_f,
                                                int osel, float* __restrict__ outf){
  __shared__ uint16_t lds_w[C_*C_];   // 32 KB: one weight matrix at a time
  const uint16_t* __restrict__ x = big_buf(xsel);

  // stage W0 (plain copies; tiny)
  {
    const uint4* src = (const uint4*)(&g_wf[2*conv][0]);
    uint4* dst = (uint4*)lds_w;
    #pragma unroll
    for (int i=0;i<8;++i) dst[i*256 + threadIdx.x] = src[i*256 + threadIdx.x];
  }

  const int wv = threadIdx.x>>6, lane = threadIdx.x&63;
  const int quad = lane>>4, l15 = lane&15;
  const int mbase = blockIdx.x*128 + wv*32;   // 2 m-tiles of 16 rows per wave

  // xf loads issued early: their latency hides under the gather
  FragCvt xf[2][4];
  #pragma unroll
  for (int mt=0;mt<2;++mt)
    #pragma unroll
    for (int ks=0;ks<4;++ks){
      size_t ad = (size_t)(mbase + mt*16 + l15)*C_ + ks*32 + quad*8;
      xf[mt][ks].u = *(const uint4*)(x + ad);
    }

  // ---- gather z = sum of neighbor rows, f32 accumulate -> bf16 fragments ----
  uint4 zf[2][4];
  const uint16_t* xb = x + (size_t)quad*8;
  #pragma unroll
  for (int mt=0;mt<2;++mt){
    int v = (mbase>>4) + mt;
    int beg = g_rowptr[v], end = g_rowptr[v+1];
    float a[4][8];
    #pragma unroll
    for (int ks=0;ks<4;++ks)
      #pragma unroll
      for (int e=0;e<8;++e) a[ks][e] = 0.f;
    int p = beg;
    for (; p+1<end; p+=2){
      int j0 = g_adj[p], j1 = g_adj[p+1];
      const uint16_t* r0 = xb + ((size_t)j0*B_ + l15)*C_;
      const uint16_t* r1 = xb + ((size_t)j1*B_ + l15)*C_;
      uint4 u0[4], u1[4];
      #pragma unroll
      for (int ks=0;ks<4;++ks) u0[ks] = *(const uint4*)(r0 + ks*32);
      #pragma unroll
      for (int ks=0;ks<4;++ks) u1[ks] = *(const uint4*)(r1 + ks*32);
      #pragma unroll
      for (int ks=0;ks<4;++ks){
        a[ks][0]+=bf_lo(u0[ks].x); a[ks][1]+=bf_hi(u0[ks].x);
        a[ks][2]+=bf_lo(u0[ks].y); a[ks][3]+=bf_hi(u0[ks].y);
        a[ks][4]+=bf_lo(u0[ks].z); a[ks][5]+=bf_hi(u0[ks].z);
        a[ks][6]+=bf_lo(u0[ks].w); a[ks][7]+=bf_hi(u0[ks].w);
        a[ks][0]+=bf_lo(u1[ks].x); a[ks][1]+=bf_hi(u1[ks].x);
        a[ks][2]+=bf_lo(u1[ks].y); a[ks][3]+=bf_hi(u1[ks].y);
        a[ks][4]+=bf_lo(u1[ks].z); a[ks][5]+=bf_hi(u1[ks].z);
        a[ks][6]+=bf_lo(u1[ks].w); a[ks][7]+=bf_hi(u1[ks].w);
      }
    }
    if (p<end){
      int j0 = g_adj[p];
      const uint16_t* r0 = xb + ((size_t)j0*B_ + l15)*C_;
      #pragma unroll
      for (int ks=0;ks<4;++ks){
        uint4 u0 = *(const uint4*)(r0 + ks*32);
        a[ks][0]+=bf_lo(u0.x); a[ks][1]+=bf_hi(u0.x);
        a[ks][2]+=bf_lo(u0.y); a[ks][3]+=bf_hi(u0.y);
        a[ks][4]+=bf_lo(u0.z); a[ks][5]+=bf_hi(u0.z);
        a[ks][6]+=bf_lo(u0.w); a[ks][7]+=bf_hi(u0.w);
      }
    }
    #pragma unroll
    for (int ks=0;ks<4;++ks){
      uint4 z;
      z.x = pk2(a[ks][0],a[ks][1]);
      z.y = pk2(a[ks][2],a[ks][3]);
      z.z = pk2(a[ks][4],a[ks][5]);
      z.w = pk2(a[ks][6],a[ks][7]);
      zf[mt][ks] = z;
    }
  }

  f32x4 acc[2][8];
  #pragma unroll
  for (int mt=0;mt<2;++mt)
    #pragma unroll
    for (int nt=0;nt<8;++nt) acc[mt][nt] = (f32x4){0.f,0.f,0.f,0.f};

  __syncthreads();            // W0 staged
  // ---- W0 pass: acc += W0^T-tiles x xf ----
  #pragma unroll
  for (int nt=0;nt<8;++nt){
    #pragma unroll
    for (int ks=0;ks<4;++ks){
      FragCvt wf; wf.u = *(const uint4*)&lds_w[((nt*4+ks)*64+lane)*8];
      acc[0][nt] = __builtin_amdgcn_mfma_f32_16x16x32_bf16(wf.v, xf[0][ks].v, acc[0][nt], 0,0,0);
      acc[1][nt] = __builtin_amdgcn_mfma_f32_16x16x32_bf16(wf.v, xf[1][ks].v, acc[1][nt], 0,0,0);
    }
  }
  __syncthreads();            // all waves done reading W0
  // stage W1
  {
    const uint4* src = (const uint4*)(&g_wf[2*conv+1][0]);
    uint4* dst = (uint4*)lds_w;
    #pragma unroll
    for (int i=0;i<8;++i) dst[i*256 + threadIdx.x] = src[i*256 + threadIdx.x];
  }
  __syncthreads();            // W1 staged
  // ---- W1 pass: acc += W1^T-tiles x zf ----
  #pragma unroll
  for (int nt=0;nt<8;++nt){
    #pragma unroll
    for (int ks=0;ks<4;++ks){
      FragCvt wf; wf.u = *(const uint4*)&lds_w[((nt*4+ks)*64+lane)*8];
      FragCvt zc0, zc1; zc0.u = zf[0][ks]; zc1.u = zf[1][ks];
      acc[0][nt] = __builtin_amdgcn_mfma_f32_16x16x32_bf16(wf.v, zc0.v, acc[0][nt], 0,0,0);
      acc[1][nt] = __builtin_amdgcn_mfma_f32_16x16x32_bf16(wf.v, zc1.v, acc[1][nt], 0,0,0);
    }
  }

  // ---- epilogue ----
  uint16_t* oint = big_buf(osel==3 ? 0 : osel);  // dummy for osel==3
  #pragma unroll
  for (int mt=0;mt<2;++mt){
    int mrow = mbase + mt*16 + l15;
    int vv = (mbase + mt*16) >> 4;       // B_==16: one m-tile == one vertex, all batches
    #pragma unroll
    for (int nt=0;nt<8;++nt){
      int colb = nt*16 + quad*4;
      f32x4 bu = *(const f32x4*)(bias_f + colb);
      float r0 = acc[mt][nt][0] + bu[0];
      float r1 = acc[mt][nt][1] + bu[1];
      float r2 = acc[mt][nt][2] + bu[2];
      float r3 = acc[mt][nt][3] + bu[3];
      if (osel==3){
        // final: += d residual (bf16), write f32 [B,V,C]
        uint2 du = *(const uint2*)(g_bufD + (size_t)mrow*C_ + colb);
        r0 += bf_lo(du.x); r1 += bf_hi(du.x); r2 += bf_lo(du.y); r3 += bf_hi(du.y);
        f32x4 o = { r0, r1, r2, r3 };
        *(f32x4*)(outf + ((size_t)l15*V_ + vv)*C_ + colb) = o;   // b = l15
      } else {
        uint2 o = { pk2(r0,r1), pk2(r2,r3) };
        *(uint2*)(oint + (size_t)mrow*C_ + colb) = o;            // [V,B,C] bf16 internal
      }
    }
  }
}

extern "C" void kernel_launch(void* const* d_in, const int* in_sizes, int n_in,
                              void* d_out, int out_size, void* d_ws, size_t ws_size,
                              hipStream_t stream) {
  const float* feat = (const float*)d_in[0];
  const float* vpos = (const float*)d_in[1];
  const float* vpad = (const float*)d_in[2];
  const int*   edges= (const int*)d_in[3];
  const float* w0_1 = (const float*)d_in[4];
  const float* b0_1 = (const float*)d_in[5];
  const float* w1_1 = (const float*)d_in[6];
  const float* w0_2 = (const float*)d_in[7];
  const float* b0_2 = (const float*)d_in[8];
  const float* w1_2 = (const float*)d_in[9];
  const float* w0_3 = (const float*)d_in[10];
  const float* b0_3 = (const float*)d_in[11];
  const float* w1_3 = (const float*)d_in[12];
  float* outp = (float*)d_out;

  hipLaunchKernelGGL(k_zero,      dim3((V_+255)/256), dim3(256), 0, stream);
  hipLaunchKernelGGL(k_count,     dim3((E_+255)/256), dim3(256), 0, stream, edges);
  hipLaunchKernelGGL(k_scan1,     dim3(40),           dim3(1024),0, stream);
  hipLaunchKernelGGL(k_scan2,     dim3(1),            dim3(64),  0, stream);
  hipLaunchKernelGGL(k_scan3,     dim3(40),           dim3(1024),0, stream);
  hipLaunchKernelGGL(k_fill,      dim3((E_+255)/256), dim3(256), 0, stream, edges);
  hipLaunchKernelGGL(k_transpose, dim3((B_*H_*W_*C_)/256), dim3(256), 0, stream, feat);
  hipLaunchKernelGGL(k_wprep,     dim3(48),           dim3(256), 0, stream,
                     w0_1, w1_1, w0_2, w1_2, w0_3, w1_3);
  hipLaunchKernelGGL(k_vertalign, dim3(V_),           dim3(256), 0, stream, vpos, vpad);
  // conv1: g (bufA) -> d (bufD), fused aggregate
  hipLaunchKernelGGL(k_conv,      dim3(M_/128), dim3(256), 0, stream, 0, 0, b0_1, 2, outp);
  // conv2: d (bufD) -> t (bufA)
  hipLaunchKernelGGL(k_conv,      dim3(M_/128), dim3(256), 0, stream, 1, 2, b0_2, 0, outp);
  // conv3: t (bufA) -> out ([B,V,C] f32) with +d residual
  hipLaunchKernelGGL(k_conv,      dim3(M_/128), dim3(256), 0, stream, 2, 0, b0_3, 3, outp);
}